// Round 5
// baseline (301.056 us; speedup 1.0000x reference)
//
#include <hip/hip_runtime.h>
#include <math.h>

#define W 32

// One re-upload step: RX(data) then RY(theta0) then RZ(theta1),
// as real 3D rotations of the Bloch vector. v_sin/v_cos take revolutions.
// Uses/updates local vars rx, ry, rz declared by QROW.
#define QSTEP(xt, t)                                                  \
    {                                                                 \
        const float rev = (xt) * 0.15915494309189535f;                \
        const float sx = __builtin_amdgcn_sinf(rev);                  \
        const float cx = __builtin_amdgcn_cosf(rev);                  \
        const float y1 = cx * ry - sx * rz;                           \
        const float z1 = sx * ry + cx * rz;                           \
        const float4 k = k_tab[(t)];                                  \
        const float x1 = k.x * rx + k.y * z1;                         \
        const float z2 = k.x * z1 - k.y * rx;                         \
        rx = k.z * x1 - k.w * y1;                                     \
        ry = k.w * x1 + k.z * y1;                                     \
        rz = z2;                                                      \
    }

#define QSTEP4(v, tb) \
    QSTEP((v).x, (tb) + 0) QSTEP((v).y, (tb) + 1) \
    QSTEP((v).z, (tb) + 2) QSTEP((v).w, (tb) + 3)

// NOTE: internal vars are rx/ry/rz — callers MUST pass differently-named
// output lvalues (R3 failed from exactly this shadowing).
#define QROW(xr, rxv, ryv, rzv)                                       \
    {                                                                 \
        const float4 v0 = (xr)[0];                                    \
        const float4 v1 = (xr)[1];                                    \
        const float4 v2 = (xr)[2];                                    \
        const float4 v3 = (xr)[3];                                    \
        const float4 v4 = (xr)[4];                                    \
        const float4 v5 = (xr)[5];                                    \
        const float4 v6 = (xr)[6];                                    \
        const float4 v7 = (xr)[7];                                    \
        float rx = 0.0f, ry = 0.0f, rz = 1.0f;                        \
        QSTEP4(v0, 0)                                                 \
        QSTEP4(v1, 4)                                                 \
        QSTEP4(v2, 8)                                                 \
        QSTEP4(v3, 12)                                                \
        QSTEP4(v4, 16)                                                \
        QSTEP4(v5, 20)                                                \
        QSTEP4(v6, 24)                                                \
        QSTEP4(v7, 28)                                                \
        (rxv) = rx; (ryv) = ry; (rzv) = rz;                           \
    }

__global__ __launch_bounds__(256) void qsim_bloch_kernel(
    const float* __restrict__ x, const float* __restrict__ theta,
    const float* __restrict__ w, const float* __restrict__ b,
    float* __restrict__ out, int n)
{
    __shared__ float4 k_tab[W];
    const int tid = threadIdx.x;
    if (tid < W) {
        float ty = theta[tid * 2 + 0];
        float tz = theta[tid * 2 + 1];
        k_tab[tid] = make_float4(cosf(ty), sinf(ty), cosf(tz), sinf(tz));
    }
    __syncthreads();

    const int i = blockIdx.x * blockDim.x + tid;
    if (i >= n) return;

    const float4* xr = reinterpret_cast<const float4*>(x + (size_t)i * W);
    float brx, bry, brz;
    QROW(xr, brx, bry, brz)
    out[i] = brz * w[0] + b[0];
}

extern "C" void kernel_launch(void* const* d_in, const int* in_sizes, int n_in,
                              void* d_out, int out_size, void* d_ws, size_t ws_size,
                              hipStream_t stream) {
    const float* x     = (const float*)d_in[0];
    const float* theta = (const float*)d_in[1];
    const float* w     = (const float*)d_in[2];
    const float* b     = (const float*)d_in[3];
    float* out = (float*)d_out;

    const int n = out_size;  // B
    const int block = 256;
    const int grid = (n + block - 1) / block;

    // MEASUREMENT ROUND: 5 identical, idempotent launches.
    // dur_R5 = F + 5*T_kernel; R2 anchor gave F + T_kernel = 195 us.
    // => T_kernel = (dur_R5 - 195) / 4. Next round reverts to one launch.
    for (int rep = 0; rep < 5; ++rep) {
        hipLaunchKernelGGL(qsim_bloch_kernel, dim3(grid), dim3(block), 0, stream,
                           x, theta, w, b, out, n);
    }
}

// Round 6
// 196.429 us; speedup vs baseline: 1.5326x; 1.5326x over previous
//
#include <hip/hip_runtime.h>
#include <math.h>

#define W 32
#define BLOCK 256

// One re-upload step: RX(data) then RY(theta0) then RZ(theta1),
// as real 3D rotations of the Bloch vector. v_sin/v_cos take revolutions.
// Uses/updates in-scope vars rx, ry, rz; reads k_tab from LDS.
#define QSTEP(xt, t)                                                  \
    {                                                                 \
        const float rev = (xt) * 0.15915494309189535f;                \
        const float sx = __builtin_amdgcn_sinf(rev);                  \
        const float cx = __builtin_amdgcn_cosf(rev);                  \
        const float y1 = cx * ry - sx * rz;                           \
        const float z1 = sx * ry + cx * rz;                           \
        const float4 k = k_tab[(t)];                                  \
        const float x1 = k.x * rx + k.y * z1;                         \
        const float z2 = k.x * z1 - k.y * rx;                         \
        rx = k.z * x1 - k.w * y1;                                     \
        ry = k.w * x1 + k.z * y1;                                     \
        rz = z2;                                                      \
    }

#define QSTEP4(v, tb) \
    QSTEP((v).x, (tb) + 0) QSTEP((v).y, (tb) + 1) \
    QSTEP((v).z, (tb) + 2) QSTEP((v).w, (tb) + 3)

__global__ __launch_bounds__(BLOCK) void qsim_bloch_kernel(
    const float* __restrict__ x,      // [B, 32]
    const float* __restrict__ theta,  // [32, 2]
    const float* __restrict__ w,      // [1,1]
    const float* __restrict__ b,      // [1]
    float* __restrict__ out,          // [B]
    int n)
{
    __shared__ float4 k_tab[W];
    __shared__ float4 xs[BLOCK * 8];  // 32 KiB: this block's 256 rows

    const int tid = threadIdx.x;
    if (tid < W) {
        float ty = theta[tid * 2 + 0];
        float tz = theta[tid * 2 + 1];
        k_tab[tid] = make_float4(cosf(ty), sinf(ty), cosf(tz), sinf(tz));
    }

    const int block0 = blockIdx.x * BLOCK;  // first row of this block
    float4 v0, v1, v2, v3, v4, v5, v6, v7;

    if (block0 + BLOCK <= n) {
        // Fast path: stage the block's contiguous 32 KiB with lane-contiguous
        // float4 loads (perfect coalescing: each 128B line fetched once by one
        // wave-contiguous request), XOR-swizzled by row to kill the
        // stride-128B bank conflict on the row-read below.
        const float4* xb = reinterpret_cast<const float4*>(x + (size_t)block0 * W);
#pragma unroll
        for (int kk = 0; kk < 8; ++kk) {
            const int m = tid + kk * BLOCK;       // linear float4 idx in chunk
            const int r = m >> 3;                 // row within block
            const int j = m & 7;                  // float4 col within row
            xs[(r << 3) | (j ^ (r & 7))] = xb[m];
        }
        __syncthreads();
        // Row read: lane t, col j -> bank 4*(j^(t&7)); each 8-lane group
        // covers all 32 banks -> structural minimum, no conflicts.
        v0 = xs[(tid << 3) | (0 ^ (tid & 7))];
        v1 = xs[(tid << 3) | (1 ^ (tid & 7))];
        v2 = xs[(tid << 3) | (2 ^ (tid & 7))];
        v3 = xs[(tid << 3) | (3 ^ (tid & 7))];
        v4 = xs[(tid << 3) | (4 ^ (tid & 7))];
        v5 = xs[(tid << 3) | (5 ^ (tid & 7))];
        v6 = xs[(tid << 3) | (6 ^ (tid & 7))];
        v7 = xs[(tid << 3) | (7 ^ (tid & 7))];
    } else {
        // Tail block: direct per-row loads (block-uniform branch).
        __syncthreads();
        const int i = block0 + tid;
        const float4* xr = reinterpret_cast<const float4*>(
            x + (size_t)(i < n ? i : 0) * W);
        v0 = xr[0]; v1 = xr[1]; v2 = xr[2]; v3 = xr[3];
        v4 = xr[4]; v5 = xr[5]; v6 = xr[6]; v7 = xr[7];
    }

    const int i = block0 + tid;
    if (i >= n) return;

    // Bloch vector for |0>
    float rx = 0.0f, ry = 0.0f, rz = 1.0f;

    QSTEP4(v0, 0)
    QSTEP4(v1, 4)
    QSTEP4(v2, 8)
    QSTEP4(v3, 12)
    QSTEP4(v4, 16)
    QSTEP4(v5, 20)
    QSTEP4(v6, 24)
    QSTEP4(v7, 28)

    out[i] = rz * w[0] + b[0];
}

extern "C" void kernel_launch(void* const* d_in, const int* in_sizes, int n_in,
                              void* d_out, int out_size, void* d_ws, size_t ws_size,
                              hipStream_t stream) {
    const float* x     = (const float*)d_in[0];
    const float* theta = (const float*)d_in[1];
    const float* w     = (const float*)d_in[2];
    const float* b     = (const float*)d_in[3];
    float* out = (float*)d_out;

    const int n = out_size;  // B
    const int grid = (n + BLOCK - 1) / BLOCK;
    hipLaunchKernelGGL(qsim_bloch_kernel, dim3(grid), dim3(BLOCK), 0, stream,
                       x, theta, w, b, out, n);
}